// Round 1
// baseline (113438.440 us; speedup 1.0000x reference)
//
#include <hip/hip_runtime.h>
#include <hip/hip_cooperative_groups.h>
#include <math.h>

namespace cg = cooperative_groups;

#define HDIM 1024
#define BDIM 64
#define TDIM 512
#define KIN  128
#define NBLK 256
#define NTHR 256
#define CHUNK 128   // k-values staged per LDS tile (128*64 fp32 = 32 KB)

// ---------------------------------------------------------------------------
// Transpose x[b][t][k] -> xT[t][k][b]  (so recurrent kernel loads are
// lane-coalesced with b fastest)
// ---------------------------------------------------------------------------
__global__ void transpose_x(const float* __restrict__ x, float* __restrict__ xT) {
    __shared__ float tile[KIN * (BDIM + 1)];  // +1 pad breaks bank conflicts
    const int t   = blockIdx.x;
    const int tid = threadIdx.x;
    #pragma unroll
    for (int r = 0; r < (KIN * BDIM) / NTHR; ++r) {   // 32 iters
        int idx = r * NTHR + tid;
        int b = idx >> 7;          // 0..63
        int k = idx & 127;         // 0..127
        tile[k * (BDIM + 1) + b] = x[((size_t)b * TDIM + t) * KIN + k];
    }
    __syncthreads();
    size_t base = (size_t)t * KIN * BDIM;
    #pragma unroll
    for (int r = 0; r < (KIN * BDIM) / NTHR; ++r) {
        int idx = r * NTHR + tid;
        int k = idx >> 6;          // 0..127
        int b = idx & 63;          // 0..63
        xT[base + idx] = tile[k * (BDIM + 1) + b];
    }
}

// ---------------------------------------------------------------------------
// One GEMV-phase: acc[g] += sum_k vecT[k][b] * W[iu + g*H][k]  for g=0..3
// vecT is [K][BDIM] (b fastest). W rows are wave-uniform -> scalar loads.
// ---------------------------------------------------------------------------
template <int LDW>
__device__ __forceinline__ void accum_phase(float acc[4],
                                            const float* __restrict__ vecT, int K,
                                            const float* __restrict__ W,
                                            int iu, int b, int tid, float* lds) {
    for (int c0 = 0; c0 < K; c0 += CHUNK) {
        __syncthreads();  // protect previous tile's readers
        {
            const float4* src = (const float4*)(vecT + (size_t)c0 * BDIM);
            float4*       dst = (float4*)lds;
            #pragma unroll
            for (int r = 0; r < (CHUNK * BDIM) / 4 / NTHR; ++r)   // 8 iters
                dst[r * NTHR + tid] = src[r * NTHR + tid];
        }
        __syncthreads();
        const float* w0 = W + (size_t)(iu + 0 * HDIM) * LDW + c0;
        const float* w1 = W + (size_t)(iu + 1 * HDIM) * LDW + c0;
        const float* w2 = W + (size_t)(iu + 2 * HDIM) * LDW + c0;
        const float* w3 = W + (size_t)(iu + 3 * HDIM) * LDW + c0;
        #pragma unroll
        for (int k4 = 0; k4 < CHUNK / 4; ++k4) {
            float4 a0 = *(const float4*)(w0 + k4 * 4);
            float4 a1 = *(const float4*)(w1 + k4 * 4);
            float4 a2 = *(const float4*)(w2 + k4 * 4);
            float4 a3 = *(const float4*)(w3 + k4 * 4);
            float v0 = lds[(k4 * 4 + 0) * BDIM + b];
            float v1 = lds[(k4 * 4 + 1) * BDIM + b];
            float v2 = lds[(k4 * 4 + 2) * BDIM + b];
            float v3 = lds[(k4 * 4 + 3) * BDIM + b];
            acc[0] = fmaf(v0, a0.x, acc[0]); acc[0] = fmaf(v1, a0.y, acc[0]);
            acc[0] = fmaf(v2, a0.z, acc[0]); acc[0] = fmaf(v3, a0.w, acc[0]);
            acc[1] = fmaf(v0, a1.x, acc[1]); acc[1] = fmaf(v1, a1.y, acc[1]);
            acc[1] = fmaf(v2, a1.z, acc[1]); acc[1] = fmaf(v3, a1.w, acc[1]);
            acc[2] = fmaf(v0, a2.x, acc[2]); acc[2] = fmaf(v1, a2.y, acc[2]);
            acc[2] = fmaf(v2, a2.z, acc[2]); acc[2] = fmaf(v3, a2.w, acc[2]);
            acc[3] = fmaf(v0, a3.x, acc[3]); acc[3] = fmaf(v1, a3.y, acc[3]);
            acc[3] = fmaf(v2, a3.z, acc[3]); acc[3] = fmaf(v3, a3.w, acc[3]);
        }
    }
}

__device__ __forceinline__ float sigm(float x) { return 1.0f / (1.0f + expf(-x)); }

// ---------------------------------------------------------------------------
// Fused 2-layer LSTM, software-pipelined: super-step s runs layer1 step s and
// layer2 step s-1. One grid sync per super-step (513 total).
// h state in double-buffered global rings [2][H][B]; c state in registers.
// Thread = (b = tid&63, i = blockIdx*4 + tid>>6).
// Ring convention: h^{(t)} lives in ring[t&1]; h^{(-1)} = 0 in ring[1].
// ---------------------------------------------------------------------------
__global__ void __launch_bounds__(NTHR, 1) lstm_fused(
    const float* __restrict__ xT,
    const float* __restrict__ Wih0, const float* __restrict__ Whh0,
    const float* __restrict__ bih0, const float* __restrict__ bhh0,
    const float* __restrict__ Wih1, const float* __restrict__ Whh1,
    const float* __restrict__ bih1, const float* __restrict__ bhh1,
    float* ring1, float* ring2) {
    __shared__ float lds[CHUNK * BDIM];
    const int tid = threadIdx.x;
    const int b   = tid & 63;
    const int il  = tid >> 6;  // 0..3, wave-uniform
    const int iu  = __builtin_amdgcn_readfirstlane(blockIdx.x * 4 + il);

    float bias1[4], bias2[4];
    #pragma unroll
    for (int g = 0; g < 4; ++g) {
        bias1[g] = bih0[iu + g * HDIM] + bhh0[iu + g * HDIM];
        bias2[g] = bih1[iu + g * HDIM] + bhh1[iu + g * HDIM];
    }
    // zero-init h^{(-1)} (ring[1]); each block covers exactly its 4*i x 64*b slice
    ring1[HDIM * BDIM + iu * BDIM + b] = 0.0f;
    ring2[HDIM * BDIM + iu * BDIM + b] = 0.0f;

    float c1 = 0.0f, c2 = 0.0f;
    cg::grid_group grid = cg::this_grid();
    grid.sync();

    for (int s = 0; s <= TDIM; ++s) {
        // ---- layer 1, step t = s: reads h1^{(s-1)} = ring1[(s+1)&1], x_t;
        //      writes h1^{(s)} -> ring1[s&1]
        if (s < TDIM) {
            float acc[4] = {bias1[0], bias1[1], bias1[2], bias1[3]};
            accum_phase<KIN>(acc, xT + (size_t)s * KIN * BDIM, KIN, Wih0, iu, b, tid, lds);
            accum_phase<HDIM>(acc, ring1 + (size_t)((s + 1) & 1) * HDIM * BDIM, HDIM, Whh0,
                              iu, b, tid, lds);
            float ig = sigm(acc[0]);
            float fg = sigm(acc[1]);
            float gg = tanhf(acc[2]);
            float og = sigm(acc[3]);
            c1 = fg * c1 + ig * gg;
            float h = og * tanhf(c1);
            ring1[(size_t)(s & 1) * HDIM * BDIM + iu * BDIM + b] = h;
        }
        // ---- layer 2, step t = s-1: reads h1^{(s-1)} = ring1[(s+1)&1] (written
        //      at super-step s-1, synced) and h2^{(s-2)} = ring2[s&1];
        //      writes h2^{(s-1)} -> ring2[(s+1)&1]
        if (s >= 1) {
            float acc[4] = {bias2[0], bias2[1], bias2[2], bias2[3]};
            accum_phase<HDIM>(acc, ring1 + (size_t)((s + 1) & 1) * HDIM * BDIM, HDIM, Wih1,
                              iu, b, tid, lds);
            accum_phase<HDIM>(acc, ring2 + (size_t)(s & 1) * HDIM * BDIM, HDIM, Whh1,
                              iu, b, tid, lds);
            float ig = sigm(acc[0]);
            float fg = sigm(acc[1]);
            float gg = tanhf(acc[2]);
            float og = sigm(acc[3]);
            c2 = fg * c2 + ig * gg;
            float h = og * tanhf(c2);
            ring2[(size_t)((s + 1) & 1) * HDIM * BDIM + iu * BDIM + b] = h;
        }
        grid.sync();
    }
    // final h2^{(511)} ends up in ring2[1]
}

// ---------------------------------------------------------------------------
// out[b] = dot(h2T[:, b], fc_w) + fc_b    (h2T is [H][B])
// ---------------------------------------------------------------------------
__global__ void fc_kernel(const float* __restrict__ h2T,
                          const float* __restrict__ fcw,
                          const float* __restrict__ fcb,
                          float* __restrict__ out) {
    __shared__ float red[NTHR];
    const int tid = threadIdx.x;
    const int b   = tid & 63;
    const int q   = tid >> 6;
    float s = 0.0f;
    for (int i = q * (HDIM / 4); i < (q + 1) * (HDIM / 4); ++i)
        s = fmaf(h2T[(size_t)i * BDIM + b], fcw[i], s);
    red[tid] = s;
    __syncthreads();
    if (q == 0) {
        out[b] = red[b] + red[64 + b] + red[128 + b] + red[192 + b] + fcb[0];
    }
}

// ---------------------------------------------------------------------------
extern "C" void kernel_launch(void* const* d_in, const int* in_sizes, int n_in,
                              void* d_out, int out_size, void* d_ws, size_t ws_size,
                              hipStream_t stream) {
    const float* x    = (const float*)d_in[0];
    const float* Wih0 = (const float*)d_in[1];
    const float* Whh0 = (const float*)d_in[2];
    const float* bih0 = (const float*)d_in[3];
    const float* bhh0 = (const float*)d_in[4];
    const float* Wih1 = (const float*)d_in[5];
    const float* Whh1 = (const float*)d_in[6];
    const float* bih1 = (const float*)d_in[7];
    const float* bhh1 = (const float*)d_in[8];
    const float* fcw  = (const float*)d_in[9];
    const float* fcb  = (const float*)d_in[10];
    float* out = (float*)d_out;

    // workspace layout (floats): xT [512*128*64] | ring1 [2*H*B] | ring2 [2*H*B]
    float* xT    = (float*)d_ws;
    float* ring1 = xT + (size_t)TDIM * KIN * BDIM;
    float* ring2 = ring1 + 2 * HDIM * BDIM;

    transpose_x<<<dim3(TDIM), dim3(NTHR), 0, stream>>>(x, xT);

    void* args[11];
    args[0]  = (void*)&xT;
    args[1]  = (void*)&Wih0;
    args[2]  = (void*)&Whh0;
    args[3]  = (void*)&bih0;
    args[4]  = (void*)&bhh0;
    args[5]  = (void*)&Wih1;
    args[6]  = (void*)&Whh1;
    args[7]  = (void*)&bih1;
    args[8]  = (void*)&bhh1;
    args[9]  = (void*)&ring1;
    args[10] = (void*)&ring2;
    hipLaunchCooperativeKernel(reinterpret_cast<void*>(lstm_fused), dim3(NBLK), dim3(NTHR),
                               args, 0, stream);

    fc_kernel<<<dim3(1), dim3(NTHR), 0, stream>>>(ring2 + HDIM * BDIM, fcw, fcb, out);
}

// Round 2
// 49208.231 us; speedup vs baseline: 2.3053x; 2.3053x over previous
//
#include <hip/hip_runtime.h>
#include <hip/hip_cooperative_groups.h>
#include <math.h>

namespace cg = cooperative_groups;

#define HDIM 1024
#define BDIM 64
#define TDIM 512
#define KIN  128
#define NBLK 256
#define NTHR 1024
#define HB   (HDIM * BDIM)

// ---------------------------------------------------------------------------
// Transpose x[b][t][k] -> xT[t][k][b]  (recurrent kernel reads lane-coalesced,
// b fastest)
// ---------------------------------------------------------------------------
__global__ void transpose_x(const float* __restrict__ x, float* __restrict__ xT) {
    __shared__ float tile[KIN * (BDIM + 1)];
    const int t   = blockIdx.x;
    const int tid = threadIdx.x;
    #pragma unroll
    for (int r = 0; r < (KIN * BDIM) / 256; ++r) {
        int idx = r * 256 + tid;
        int b = idx >> 7;
        int k = idx & 127;
        tile[k * (BDIM + 1) + b] = x[((size_t)b * TDIM + t) * KIN + k];
    }
    __syncthreads();
    size_t base = (size_t)t * KIN * BDIM;
    #pragma unroll
    for (int r = 0; r < (KIN * BDIM) / 256; ++r) {
        int idx = r * 256 + tid;
        int k = idx >> 6;
        int b = idx & 63;
        xT[base + idx] = tile[k * (BDIM + 1) + b];
    }
}

// ---------------------------------------------------------------------------
// Partial GEMV: wave w handles k-slice [w*K/16, (w+1)*K/16) of this part for
// all 16 rows (4 i_local x 4 gates). acc[i*4+g] += sum_k vec[k][b]*W[row][k].
// vec reads: per-lane coalesced global loads (L2-hot ring / xT).
// W reads: wave-uniform -> scalar loads.
// ---------------------------------------------------------------------------
template <int KPART, int LDW>
__device__ __forceinline__ void accum_part(float acc[16],
                                           const float* __restrict__ vec,
                                           const float* __restrict__ W,
                                           int iu_base, int w, int b) {
    constexpr int K16 = KPART / 16;
    const int k0 = w * K16;
    const float* vp = vec + (size_t)k0 * BDIM + b;
    const float* wr[16];
    #pragma unroll
    for (int i = 0; i < 4; ++i)
        #pragma unroll
        for (int g = 0; g < 4; ++g)
            wr[i * 4 + g] = W + (size_t)(iu_base + i + g * HDIM) * LDW + k0;
    #pragma unroll 4
    for (int k4 = 0; k4 < K16 / 4; ++k4) {
        float v0 = vp[(4 * k4 + 0) * BDIM];
        float v1 = vp[(4 * k4 + 1) * BDIM];
        float v2 = vp[(4 * k4 + 2) * BDIM];
        float v3 = vp[(4 * k4 + 3) * BDIM];
        #pragma unroll
        for (int r = 0; r < 16; ++r) {
            float4 wv = *(const float4*)(wr[r] + 4 * k4);
            float a = acc[r];
            a = fmaf(v0, wv.x, a);
            a = fmaf(v1, wv.y, a);
            a = fmaf(v2, wv.z, a);
            a = fmaf(v3, wv.w, a);
            acc[r] = a;
        }
    }
}

__device__ __forceinline__ float sigm(float x) { return 1.0f / (1.0f + expf(-x)); }

// ---------------------------------------------------------------------------
// Fused 2-layer LSTM, software-pipelined: super-step s runs layer1 step s and
// layer2 step s-1. Block = 1024 threads = 16 waves; block owns 4 hidden
// columns (iu_base..iu_base+3); wave w handles k-slice w/16 for all 16 rows.
// Partials reduced via LDS; waves 0..3 own the (i_local = w) state and do the
// activations + h-store. h rings are double-buffered global; c in registers.
// Ring convention: h^{(t)} in ring[t&1]; h^{(-1)} = 0 in ring[1].
// ---------------------------------------------------------------------------
__global__ void __launch_bounds__(NTHR, 4) lstm_fused(
    const float* __restrict__ xT,
    const float* __restrict__ Wih0, const float* __restrict__ Whh0,
    const float* __restrict__ bih0, const float* __restrict__ bhh0,
    const float* __restrict__ Wih1, const float* __restrict__ Whh1,
    const float* __restrict__ bih1, const float* __restrict__ bhh1,
    float* ring1, float* ring2) {
    // red4[(w*4 + i)*64 + b] = float4 over gates — 64 KB
    __shared__ float4 red4[16 * 4 * BDIM];

    const int tid = threadIdx.x;
    const int b   = tid & 63;
    const int w   = __builtin_amdgcn_readfirstlane(tid >> 6);   // 0..15
    const int iu_base = __builtin_amdgcn_readfirstlane(blockIdx.x * 4);

    // owners: waves 0..3, i_local = w
    float bias1[4], bias2[4];
    float c1 = 0.0f, c2 = 0.0f;
    if (w < 4) {
        #pragma unroll
        for (int g = 0; g < 4; ++g) {
            bias1[g] = bih0[iu_base + w + g * HDIM] + bhh0[iu_base + w + g * HDIM];
            bias2[g] = bih1[iu_base + w + g * HDIM] + bhh1[iu_base + w + g * HDIM];
        }
        // zero-init h^{(-1)} (ring[1]); block covers its 4i x 64b slice
        ring1[HB + (iu_base + w) * BDIM + b] = 0.0f;
        ring2[HB + (iu_base + w) * BDIM + b] = 0.0f;
    }

    cg::grid_group grid = cg::this_grid();
    grid.sync();

    for (int s = 0; s <= TDIM; ++s) {
        // ---- layer 1, step t = s: reads h1^{(s-1)} = ring1[(s+1)&1], x_s
        if (s < TDIM) {
            float acc[16];
            #pragma unroll
            for (int r = 0; r < 16; ++r) acc[r] = 0.0f;
            accum_part<KIN, KIN>(acc, xT + (size_t)s * KIN * BDIM, Wih0, iu_base, w, b);
            accum_part<HDIM, HDIM>(acc, ring1 + (size_t)((s + 1) & 1) * HB, Whh0,
                                   iu_base, w, b);
            #pragma unroll
            for (int i = 0; i < 4; ++i)
                red4[(w * 4 + i) * BDIM + b] =
                    make_float4(acc[i * 4 + 0], acc[i * 4 + 1], acc[i * 4 + 2], acc[i * 4 + 3]);
        }
        __syncthreads();
        if (s < TDIM && w < 4) {
            float4 gsum = make_float4(bias1[0], bias1[1], bias1[2], bias1[3]);
            #pragma unroll
            for (int wp = 0; wp < 16; ++wp) {
                float4 p = red4[(wp * 4 + w) * BDIM + b];
                gsum.x += p.x; gsum.y += p.y; gsum.z += p.z; gsum.w += p.w;
            }
            float ig = sigm(gsum.x);
            float fg = sigm(gsum.y);
            float gg = tanhf(gsum.z);
            float og = sigm(gsum.w);
            c1 = fg * c1 + ig * gg;
            float h = og * tanhf(c1);
            ring1[(size_t)(s & 1) * HB + (iu_base + w) * BDIM + b] = h;
        }
        __syncthreads();  // red4 reuse by layer 2
        // ---- layer 2, step t = s-1: reads h1^{(s-1)} = ring1[(s+1)&1],
        //      h2^{(s-2)} = ring2[s&1]; writes h2^{(s-1)} -> ring2[(s+1)&1]
        if (s >= 1) {
            float acc[16];
            #pragma unroll
            for (int r = 0; r < 16; ++r) acc[r] = 0.0f;
            accum_part<HDIM, HDIM>(acc, ring1 + (size_t)((s + 1) & 1) * HB, Wih1,
                                   iu_base, w, b);
            accum_part<HDIM, HDIM>(acc, ring2 + (size_t)(s & 1) * HB, Whh1,
                                   iu_base, w, b);
            #pragma unroll
            for (int i = 0; i < 4; ++i)
                red4[(w * 4 + i) * BDIM + b] =
                    make_float4(acc[i * 4 + 0], acc[i * 4 + 1], acc[i * 4 + 2], acc[i * 4 + 3]);
        }
        __syncthreads();
        if (s >= 1 && w < 4) {
            float4 gsum = make_float4(bias2[0], bias2[1], bias2[2], bias2[3]);
            #pragma unroll
            for (int wp = 0; wp < 16; ++wp) {
                float4 p = red4[(wp * 4 + w) * BDIM + b];
                gsum.x += p.x; gsum.y += p.y; gsum.z += p.z; gsum.w += p.w;
            }
            float ig = sigm(gsum.x);
            float fg = sigm(gsum.y);
            float gg = tanhf(gsum.z);
            float og = sigm(gsum.w);
            c2 = fg * c2 + ig * gg;
            float h = og * tanhf(c2);
            ring2[(size_t)((s + 1) & 1) * HB + (iu_base + w) * BDIM + b] = h;
        }
        grid.sync();
    }
    // final h2^{(511)} is in ring2[1]
}

// ---------------------------------------------------------------------------
// out[b] = dot(h2T[:, b], fc_w) + fc_b    (h2T is [H][B])
// ---------------------------------------------------------------------------
__global__ void fc_kernel(const float* __restrict__ h2T,
                          const float* __restrict__ fcw,
                          const float* __restrict__ fcb,
                          float* __restrict__ out) {
    __shared__ float red[256];
    const int tid = threadIdx.x;
    const int b   = tid & 63;
    const int q   = tid >> 6;
    float s = 0.0f;
    for (int i = q * (HDIM / 4); i < (q + 1) * (HDIM / 4); ++i)
        s = fmaf(h2T[(size_t)i * BDIM + b], fcw[i], s);
    red[tid] = s;
    __syncthreads();
    if (q == 0) {
        out[b] = red[b] + red[64 + b] + red[128 + b] + red[192 + b] + fcb[0];
    }
}

// ---------------------------------------------------------------------------
extern "C" void kernel_launch(void* const* d_in, const int* in_sizes, int n_in,
                              void* d_out, int out_size, void* d_ws, size_t ws_size,
                              hipStream_t stream) {
    const float* x    = (const float*)d_in[0];
    const float* Wih0 = (const float*)d_in[1];
    const float* Whh0 = (const float*)d_in[2];
    const float* bih0 = (const float*)d_in[3];
    const float* bhh0 = (const float*)d_in[4];
    const float* Wih1 = (const float*)d_in[5];
    const float* Whh1 = (const float*)d_in[6];
    const float* bih1 = (const float*)d_in[7];
    const float* bhh1 = (const float*)d_in[8];
    const float* fcw  = (const float*)d_in[9];
    const float* fcb  = (const float*)d_in[10];
    float* out = (float*)d_out;

    // workspace layout (floats): xT [512*128*64] | ring1 [2*H*B] | ring2 [2*H*B]
    float* xT    = (float*)d_ws;
    float* ring1 = xT + (size_t)TDIM * KIN * BDIM;
    float* ring2 = ring1 + 2 * HB;

    transpose_x<<<dim3(TDIM), dim3(256), 0, stream>>>(x, xT);

    void* args[11];
    args[0]  = (void*)&xT;
    args[1]  = (void*)&Wih0;
    args[2]  = (void*)&Whh0;
    args[3]  = (void*)&bih0;
    args[4]  = (void*)&bhh0;
    args[5]  = (void*)&Wih1;
    args[6]  = (void*)&Whh1;
    args[7]  = (void*)&bih1;
    args[8]  = (void*)&bhh1;
    args[9]  = (void*)&ring1;
    args[10] = (void*)&ring2;
    hipLaunchCooperativeKernel(reinterpret_cast<void*>(lstm_fused), dim3(NBLK), dim3(NTHR),
                               args, 0, stream);

    fc_kernel<<<dim3(1), dim3(256), 0, stream>>>(ring2 + HB, fcw, fcb, out);
}

// Round 3
// 19935.237 us; speedup vs baseline: 5.6903x; 2.4684x over previous
//
#include <hip/hip_runtime.h>
#include <hip/hip_cooperative_groups.h>
#include <math.h>

namespace cg = cooperative_groups;

#define HDIM 1024
#define BDIM 64
#define TDIM 512
#define KIN  128
#define NBLK 256
#define NTHR 1024
#define HB   (HDIM * BDIM)   // halfs per ring frame

typedef _Float16 f16;
typedef __attribute__((ext_vector_type(2))) _Float16 f16x2;
typedef __attribute__((ext_vector_type(8))) _Float16 f16x8;

// ---------------------------------------------------------------------------
// fp32 -> fp16 weight conversion (element pairs)
// ---------------------------------------------------------------------------
__global__ void cvt_w(const float* __restrict__ src, f16* __restrict__ dst, int n2) {
    int i = blockIdx.x * blockDim.x + threadIdx.x;
    if (i < n2) {
        float2 a = ((const float2*)src)[i];
        f16x2 o = {(f16)a.x, (f16)a.y};
        ((f16x2*)dst)[i] = o;
    }
}

// ---------------------------------------------------------------------------
// x[b][t][k] fp32 -> xP[t][k/2][b][2] fp16 (pair-packed, b fastest within pair)
// ---------------------------------------------------------------------------
__global__ void transpose_cvt_x(const float* __restrict__ x, f16* __restrict__ xP) {
    __shared__ float tile[KIN * (BDIM + 1)];
    const int t   = blockIdx.x;
    const int tid = threadIdx.x;   // 256
    #pragma unroll
    for (int r = 0; r < (KIN * BDIM) / 256; ++r) {
        int idx = r * 256 + tid;
        int b = idx >> 7;
        int k = idx & 127;
        tile[k * (BDIM + 1) + b] = x[((size_t)b * TDIM + t) * KIN + k];
    }
    __syncthreads();
    f16x2* dst = (f16x2*)xP + (size_t)t * (KIN / 2) * BDIM;
    #pragma unroll
    for (int r = 0; r < (KIN / 2) * BDIM / 256; ++r) {   // 16 iters
        int idx = r * 256 + tid;
        int p = idx >> 6;       // pair index 0..63
        int b = idx & 63;
        f16x2 o = {(f16)tile[(2 * p) * (BDIM + 1) + b],
                   (f16)tile[(2 * p + 1) * (BDIM + 1) + b]};
        dst[idx] = o;
    }
}

// ---------------------------------------------------------------------------
// Partial GEMV with fp16 dot2: wave w handles k-slice [w*K/16,(w+1)*K/16) for
// 16 rows (4 i_local x 4 gates). vecP is pair-packed [K/2][64][2] fp16.
// Weight rows wave-uniform (scalar 16B loads); activations 4B half2 loads.
// ---------------------------------------------------------------------------
template <int KPART, int LDW>
__device__ __forceinline__ void accum_fp16(float acc[16],
                                           const f16* __restrict__ vecP,
                                           const f16* __restrict__ Wc,
                                           int iu_base, int w, int b) {
    constexpr int K16 = KPART / 16;
    const int k0 = w * K16;
    const f16* vp = vecP + (size_t)(k0 >> 1) * (2 * BDIM) + b * 2;
    const f16* wr[16];
    #pragma unroll
    for (int i = 0; i < 4; ++i)
        #pragma unroll
        for (int g = 0; g < 4; ++g)
            wr[i * 4 + g] = Wc + (size_t)(iu_base + i + g * HDIM) * LDW + k0;
    #pragma unroll 2
    for (int k8 = 0; k8 < K16 / 8; ++k8) {
        f16x2 v0 = *(const f16x2*)(vp + (k8 * 4 + 0) * (2 * BDIM));
        f16x2 v1 = *(const f16x2*)(vp + (k8 * 4 + 1) * (2 * BDIM));
        f16x2 v2 = *(const f16x2*)(vp + (k8 * 4 + 2) * (2 * BDIM));
        f16x2 v3 = *(const f16x2*)(vp + (k8 * 4 + 3) * (2 * BDIM));
        #pragma unroll
        for (int r = 0; r < 16; ++r) {
            f16x8 wv = *(const f16x8*)(wr[r] + k8 * 8);
            float a = acc[r];
            a = __builtin_amdgcn_fdot2((f16x2){wv[0], wv[1]}, v0, a, false);
            a = __builtin_amdgcn_fdot2((f16x2){wv[2], wv[3]}, v1, a, false);
            a = __builtin_amdgcn_fdot2((f16x2){wv[4], wv[5]}, v2, a, false);
            a = __builtin_amdgcn_fdot2((f16x2){wv[6], wv[7]}, v3, a, false);
            acc[r] = a;
        }
    }
}

__device__ __forceinline__ float sigm(float x) { return 1.0f / (1.0f + expf(-x)); }

// ---------------------------------------------------------------------------
// Fused 2-layer LSTM, software-pipelined (super-step s = layer1 step s +
// layer2 step s-1, one grid sync per super-step). Block = 16 waves, owns 4
// hidden cols; wave w covers k-slice w/16 for all 16 rows; LDS reduction;
// owner waves 0..3 hold c in fp32 registers, store h as fp16 pair-packed.
// Ring convention: h^{(t)} in ring[t&1]; h^{(-1)} = 0 in ring[1].
// ---------------------------------------------------------------------------
__global__ void __launch_bounds__(NTHR, 4) lstm_fused(
    const f16* __restrict__ xP,
    const f16* __restrict__ Wc0, const f16* __restrict__ Wh0,
    const float* __restrict__ bih0, const float* __restrict__ bhh0,
    const f16* __restrict__ Wc1, const f16* __restrict__ Wh1,
    const float* __restrict__ bih1, const float* __restrict__ bhh1,
    f16* ring1, f16* ring2) {
    __shared__ float4 red4[16 * 4 * BDIM];   // 64 KB

    const int tid = threadIdx.x;
    const int b   = tid & 63;
    const int w   = __builtin_amdgcn_readfirstlane(tid >> 6);   // 0..15
    const int iu_base = __builtin_amdgcn_readfirstlane(blockIdx.x * 4);

    float bias1[4], bias2[4];
    float c1 = 0.0f, c2 = 0.0f;
    if (w < 4) {
        const int i = iu_base + w;
        #pragma unroll
        for (int g = 0; g < 4; ++g) {
            bias1[g] = bih0[i + g * HDIM] + bhh0[i + g * HDIM];
            bias2[g] = bih1[i + g * HDIM] + bhh1[i + g * HDIM];
        }
        size_t off = (size_t)HB + ((size_t)(i >> 1) * BDIM + b) * 2 + (i & 1);
        ring1[off] = (f16)0.0f;
        ring2[off] = (f16)0.0f;
    }

    cg::grid_group grid = cg::this_grid();
    grid.sync();

    for (int s = 0; s <= TDIM; ++s) {
        // ---- layer 1, step t = s: reads h1^{(s-1)} = ring1[(s+1)&1], x_s
        if (s < TDIM) {
            float acc[16];
            #pragma unroll
            for (int r = 0; r < 16; ++r) acc[r] = 0.0f;
            accum_fp16<KIN, KIN>(acc, xP + (size_t)s * (KIN / 2) * (2 * BDIM),
                                 Wc0, iu_base, w, b);
            accum_fp16<HDIM, HDIM>(acc, ring1 + (size_t)((s + 1) & 1) * HB, Wh0,
                                   iu_base, w, b);
            #pragma unroll
            for (int i = 0; i < 4; ++i)
                red4[(w * 4 + i) * BDIM + b] =
                    make_float4(acc[i * 4 + 0], acc[i * 4 + 1], acc[i * 4 + 2], acc[i * 4 + 3]);
        }
        __syncthreads();
        if (s < TDIM && w < 4) {
            float4 gsum = make_float4(bias1[0], bias1[1], bias1[2], bias1[3]);
            #pragma unroll
            for (int wp = 0; wp < 16; ++wp) {
                float4 p = red4[(wp * 4 + w) * BDIM + b];
                gsum.x += p.x; gsum.y += p.y; gsum.z += p.z; gsum.w += p.w;
            }
            float ig = sigm(gsum.x);
            float fg = sigm(gsum.y);
            float gg = tanhf(gsum.z);
            float og = sigm(gsum.w);
            c1 = fg * c1 + ig * gg;
            float h = og * tanhf(c1);
            const int i = iu_base + w;
            ring1[(size_t)(s & 1) * HB + ((size_t)(i >> 1) * BDIM + b) * 2 + (i & 1)] = (f16)h;
        }
        __syncthreads();  // red4 reuse by layer 2
        // ---- layer 2, step t = s-1
        if (s >= 1) {
            float acc[16];
            #pragma unroll
            for (int r = 0; r < 16; ++r) acc[r] = 0.0f;
            accum_fp16<HDIM, HDIM>(acc, ring1 + (size_t)((s + 1) & 1) * HB, Wc1,
                                   iu_base, w, b);
            accum_fp16<HDIM, HDIM>(acc, ring2 + (size_t)(s & 1) * HB, Wh1,
                                   iu_base, w, b);
            #pragma unroll
            for (int i = 0; i < 4; ++i)
                red4[(w * 4 + i) * BDIM + b] =
                    make_float4(acc[i * 4 + 0], acc[i * 4 + 1], acc[i * 4 + 2], acc[i * 4 + 3]);
        }
        __syncthreads();
        if (s >= 1 && w < 4) {
            float4 gsum = make_float4(bias2[0], bias2[1], bias2[2], bias2[3]);
            #pragma unroll
            for (int wp = 0; wp < 16; ++wp) {
                float4 p = red4[(wp * 4 + w) * BDIM + b];
                gsum.x += p.x; gsum.y += p.y; gsum.z += p.z; gsum.w += p.w;
            }
            float ig = sigm(gsum.x);
            float fg = sigm(gsum.y);
            float gg = tanhf(gsum.z);
            float og = sigm(gsum.w);
            c2 = fg * c2 + ig * gg;
            float h = og * tanhf(c2);
            const int i = iu_base + w;
            ring2[(size_t)((s + 1) & 1) * HB + ((size_t)(i >> 1) * BDIM + b) * 2 + (i & 1)] = (f16)h;
        }
        grid.sync();
    }
    // final h2^{(511)} is in ring2[1]
}

// ---------------------------------------------------------------------------
// out[b] = dot(h2[:, b], fc_w) + fc_b.  h2 pair-packed fp16 [H/2][64][2].
// ---------------------------------------------------------------------------
__global__ void fc_kernel(const f16* __restrict__ h2f,
                          const float* __restrict__ fcw,
                          const float* __restrict__ fcb,
                          float* __restrict__ out) {
    __shared__ float red[256];
    const int tid = threadIdx.x;
    const int b   = tid & 63;
    const int q   = tid >> 6;
    float s = 0.0f;
    for (int i = q * (HDIM / 4); i < (q + 1) * (HDIM / 4); ++i) {
        float v = (float)h2f[((size_t)(i >> 1) * BDIM + b) * 2 + (i & 1)];
        s = fmaf(v, fcw[i], s);
    }
    red[tid] = s;
    __syncthreads();
    if (q == 0) {
        out[b] = red[b] + red[64 + b] + red[128 + b] + red[192 + b] + fcb[0];
    }
}

// ---------------------------------------------------------------------------
extern "C" void kernel_launch(void* const* d_in, const int* in_sizes, int n_in,
                              void* d_out, int out_size, void* d_ws, size_t ws_size,
                              hipStream_t stream) {
    const float* x    = (const float*)d_in[0];
    const float* Wih0 = (const float*)d_in[1];
    const float* Whh0 = (const float*)d_in[2];
    const float* bih0 = (const float*)d_in[3];
    const float* bhh0 = (const float*)d_in[4];
    const float* Wih1 = (const float*)d_in[5];
    const float* Whh1 = (const float*)d_in[6];
    const float* bih1 = (const float*)d_in[7];
    const float* bhh1 = (const float*)d_in[8];
    const float* fcw  = (const float*)d_in[9];
    const float* fcb  = (const float*)d_in[10];
    float* out = (float*)d_out;

    // workspace (halfs): xP [512*64*128] | Wc0 [4H*128] | Wh0 [4H*H] |
    //                    Wc1 [4H*H] | Wh1 [4H*H] | ring1 [2*HB] | ring2 [2*HB]
    f16* xP   = (f16*)d_ws;
    f16* Wc0  = xP + (size_t)TDIM * KIN * BDIM;
    f16* Wh0  = Wc0 + (size_t)4 * HDIM * KIN;
    f16* Wc1  = Wh0 + (size_t)4 * HDIM * HDIM;
    f16* Wh1  = Wc1 + (size_t)4 * HDIM * HDIM;
    f16* ring1 = Wh1 + (size_t)4 * HDIM * HDIM;
    f16* ring2 = ring1 + 2 * HB;

    {
        int n2 = 4 * HDIM * KIN / 2;
        cvt_w<<<dim3((n2 + 255) / 256), dim3(256), 0, stream>>>(Wih0, Wc0, n2);
        n2 = 4 * HDIM * HDIM / 2;
        cvt_w<<<dim3((n2 + 255) / 256), dim3(256), 0, stream>>>(Whh0, Wh0, n2);
        cvt_w<<<dim3((n2 + 255) / 256), dim3(256), 0, stream>>>(Wih1, Wc1, n2);
        cvt_w<<<dim3((n2 + 255) / 256), dim3(256), 0, stream>>>(Whh1, Wh1, n2);
    }
    transpose_cvt_x<<<dim3(TDIM), dim3(256), 0, stream>>>(x, xP);

    void* args[11];
    args[0]  = (void*)&xP;
    args[1]  = (void*)&Wc0;
    args[2]  = (void*)&Wh0;
    args[3]  = (void*)&bih0;
    args[4]  = (void*)&bhh0;
    args[5]  = (void*)&Wc1;
    args[6]  = (void*)&Wh1;
    args[7]  = (void*)&bih1;
    args[8]  = (void*)&bhh1;
    args[9]  = (void*)&ring1;
    args[10] = (void*)&ring2;
    hipLaunchCooperativeKernel(reinterpret_cast<void*>(lstm_fused), dim3(NBLK), dim3(NTHR),
                               args, 0, stream);

    fc_kernel<<<dim3(1), dim3(256), 0, stream>>>(ring2 + HB, fcw, fcb, out);
}